// Round 19
// baseline (2161.288 us; speedup 1.0000x reference)
//
#include <hip/hip_runtime.h>

#define T_STEPS 1000
#define DT 0.1f
#define HIDDEN 128
#define N_AGENTS 1024

typedef float v2f __attribute__((ext_vector_type(2)));
typedef float v4f __attribute__((ext_vector_type(4)));

// tanh(x) = 1 - 2/(exp(2x)+1); exact at +/-inf, ~1e-7 rel error.
__device__ __forceinline__ float tanh_fast(float x) {
    float e = __expf(2.0f * x);
    return 1.0f - 2.0f * __builtin_amdgcn_rcpf(e + 1.0f);
}

// Opaque 16B load (R6-R18 proven residency mechanism): asm output can't be
// remat'd/sunk, so the weights stay register-file-resident (AGPRs).
__device__ __forceinline__ v4f opaque_load16(const float* p) {
    v4f v;
    asm volatile("global_load_dwordx4 %0, %1, off\n\ts_waitcnt vmcnt(0)"
                 : "=v"(v)
                 : "v"((unsigned long long)(uintptr_t)p)
                 : "memory");
    return v;
}

__device__ __forceinline__ float uniformf(float v) {
    return __builtin_bit_cast(float,
        __builtin_amdgcn_readfirstlane(__builtin_bit_cast(int, v)));
}

// 64-lane sum on the VALU pipe via DPP row ops (R11-R18 verified).
__device__ __forceinline__ float wave_sum_dpp(float x) {
    float t;
    #define DPPADD(ctrl, rmask)                                              \
        t = __builtin_bit_cast(float, __builtin_amdgcn_update_dpp(           \
                0, __builtin_bit_cast(int, x), ctrl, rmask, 0xf, false));    \
        x += t;
    DPPADD(0x111, 0xf)
    DPPADD(0x112, 0xf)
    DPPADD(0x114, 0xf)
    DPPADD(0x118, 0xf)
    DPPADD(0x142, 0xa)
    DPPADD(0x143, 0xc)
    #undef DPPADD
    return __builtin_bit_cast(float,
        __builtin_amdgcn_readlane(__builtin_bit_cast(int, x), 63));
}

// Pre-pack W1 into component-paired layout (R14-R18 verified):
//   pw[row*128 + 2a,2a+1]   = (Wx[a], Wy[a])    a = 0..31
//   pw[row*128 + 64+2a,+1]  = (Wz[a], Wc[a])
__global__ void pack_kernel(const float* __restrict__ W1,
                            float* __restrict__ pw) {
    const int row = blockIdx.x;     // 128
    const int a   = threadIdx.x;    // 32
    const float* rp = W1 + row * 128;
    float* out = pw + row * 128;
    out[2*a]          = rp[3*a];
    out[2*a + 1]      = rp[3*a + 1];
    out[64 + 2*a]     = rp[3*a + 2];
    out[64 + 2*a + 1] = rp[96 + a];
}

// SINGLE-WAVE AGENT — zero barriers, zero LDS, one code path.
// R18 post-mortem: at equal occupancy the 8x barrier cut changed nothing;
// the stall was role imbalance (h1 idle ~2/3 of each window) + dual ~19KB
// unrolled bodies thrashing the 32KB I-cache + cross-wave plumbing. All of
// it existed only to split a working set that fits ONE wave at 1 wave/SIMD:
//   waves_per_eu(1,1) -> 512-reg unified budget. 128 pinned v2f weights ->
//   AGPR file (256, exactly capacity; R13/R14 showed pk_fma sources AGPRs
//   with no copy tax). Ring 2 rows x 40 v2f = 160 arch + ~40 working ~= 200
//   arch <= 256. 1024 agents x 1 wave = 1024 waves = exactly 1/SIMD.
// Per lane: rows (lane, lane+64), ALL 32 ages. Per step: consume slot j,
// DPP layer-2 (in-wave), tail once, push e(t+1) into slots j+1..j+32
// (128 pk_fma). 8-step unroll -> compile-time indices (max j+32 = 39);
// rotate ring by 8 (64 v2f movs) per window. Body ~13KB, fits I-cache.
__global__ __launch_bounds__(64)
__attribute__((amdgpu_waves_per_eu(1, 1)))
void sim_kernel(const float* __restrict__ target_pos,
                const float* __restrict__ logsigma,
                const float* __restrict__ x_inits,
                const float* __restrict__ pw,
                const float* __restrict__ b1,
                const float* __restrict__ W2,
                const float* __restrict__ b2,
                float2* __restrict__ ws) {
    const int agent = blockIdx.x;
    const int lane  = threadIdx.x;   // 0..63
    const int rowA  = lane;
    const int rowB  = lane + 64;

    const float tx0 = uniformf(target_pos[0]), ty0 = uniformf(target_pos[1]);
    const float tx1 = uniformf(target_pos[2]), ty1 = uniformf(target_pos[3]);
    const float tx2 = uniformf(target_pos[4]), ty2 = uniformf(target_pos[5]);
    const float is0 = uniformf(1.0f / expf(logsigma[0]));
    const float is1 = uniformf(1.0f / expf(logsigma[1]));
    const float is2 = uniformf(1.0f / expf(logsigma[2]));

    // All 32 ages, rows A and B: 128 v2f = 256 floats, pinned via opaque
    // 16B loads (2 pairs per load).
    v2f WxyA[32], WzcA[32], WxyB[32], WzcB[32];
    {
        const float* baseA = pw + rowA * 128;
        const float* baseB = pw + rowB * 128;
        #pragma unroll
        for (int i = 0; i < 16; ++i) {
            v4f q;
            q = opaque_load16(baseA + 4 * i);
            WxyA[2*i] = q.xy;  WxyA[2*i+1] = q.zw;
            q = opaque_load16(baseA + 64 + 4 * i);
            WzcA[2*i] = q.xy;  WzcA[2*i+1] = q.zw;
            q = opaque_load16(baseB + 4 * i);
            WxyB[2*i] = q.xy;  WxyB[2*i+1] = q.zw;
            q = opaque_load16(baseB + 64 + 4 * i);
            WzcB[2*i] = q.xy;  WzcB[2*i+1] = q.zw;
        }
    }
    const float b1A = b1[rowA], b1B = b1[rowB];
    const float w20A = W2[rowA], w20B = W2[rowB];
    const float w21A = W2[HIDDEN + rowA], w21B = W2[HIDDEN + rowB];
    const float b2x = uniformf(b2[0]), b2y = uniformf(b2[1]);

    auto conc = [&](float px, float py) {
        float dx0 = px - tx0, dy0 = py - ty0;
        float dx1 = px - tx1, dy1 = py - ty1;
        float dx2 = px - tx2, dy2 = py - ty2;
        float cc  = is0 * __expf(-(dx0*dx0 + dy0*dy0) * is0);
        cc       += is1 * __expf(-(dx1*dx1 + dy1*dy1) * is1);
        cc       += is2 * __expf(-(dx2*dx2 + dy2*dy2) * is2);
        return cc;
    };

    float x  = uniformf(x_inits[3 * agent]);
    float y  = uniformf(x_inits[3 * agent + 1]);
    float th = uniformf(x_inits[3 * agent + 2]);
    float c  = conc(x, y);

    // Pending ring: 40 slots/row (8-step unroll + 32 ages). Slot j holds
    // h_pre contributions for step (window_base + j).
    v2f RA[40], RB[40];
    {
        v2f exy0 = {x, y}, ezc0 = {th, c};
        v2f aA = {0.f, 0.f}, aB = {0.f, 0.f};
        #pragma unroll
        for (int k = 31; k >= 0; --k) {
            aA = WxyA[k] * exy0 + aA;  aA = WzcA[k] * ezc0 + aA;
            aB = WxyB[k] * exy0 + aB;  aB = WzcB[k] * ezc0 + aB;
            RA[k] = aA;  RB[k] = aB;
        }
        #pragma unroll
        for (int i = 32; i < 40; ++i) { RA[i] = (v2f){0.f,0.f}; RB[i] = (v2f){0.f,0.f}; }
    }

    float S_c = 0.f, S_u = 0.f;

    #pragma unroll 1
    for (int tt = 0; tt < 125; ++tt) {
        #pragma unroll
        for (int j = 0; j < 8; ++j) {
            // ---- consume slot j: layer 1 + DPP layer 2 ----
            float hA = fmaxf((RA[j].x + RA[j].y) + b1A, 0.f);
            float hB = fmaxf((RB[j].x + RB[j].y) + b1B, 0.f);
            float s0 = wave_sum_dpp(fmaf(w20A, hA, w20B * hB));
            float s1 = wave_sum_dpp(fmaf(w21A, hA, w21B * hB));

            // ---- tail (once; no other wave to sync with) ----
            float v  = tanh_fast(s0 + b2x);
            float wv = tanh_fast(s1 + b2y);
            S_u += v * v + wv * wv;
            float sn = __sinf(th), cs = __cosf(th);
            float dv = DT * v;
            x  = fmaf(dv, cs, x);
            y  = fmaf(dv, sn, y);
            th = fmaf(DT, wv, th);
            c  = conc(x, y);
            S_c += c;

            // ---- push e(t+1) into slots j+1..j+32: 128 v_pk_fma_f32 ----
            v2f exy = {x, y}, ezc = {th, c};
            #pragma unroll
            for (int k = 0; k < 32; ++k) {
                const int m = j + 1 + k;   // <= 39, compile-time
                RA[m] = WxyA[k] * exy + RA[m];  RA[m] = WzcA[k] * ezc + RA[m];
                RB[m] = WxyB[k] * exy + RB[m];  RB[m] = WzcB[k] * ezc + RB[m];
            }
        }
        // ---- rotate ring by 8 ----
        #pragma unroll
        for (int i = 0; i < 32; ++i) { RA[i] = RA[i + 8]; RB[i] = RB[i + 8]; }
        #pragma unroll
        for (int i = 32; i < 40; ++i) { RA[i] = (v2f){0.f,0.f}; RB[i] = (v2f){0.f,0.f}; }
    }

    if (lane == 0) ws[agent] = make_float2(S_c, S_u);
}

__global__ void reduce_kernel(const float2* __restrict__ ws,
                              float* __restrict__ out) {
    const int tid = threadIdx.x;  // 256 threads
    float sc = 0.f, su = 0.f;
    for (int i = tid; i < N_AGENTS; i += 256) {
        float2 v = ws[i];
        sc += v.x;
        su += v.y;
    }
    #pragma unroll
    for (int off = 32; off > 0; off >>= 1) {
        sc += __shfl_xor(sc, off);
        su += __shfl_xor(su, off);
    }
    __shared__ float2 partw[4];
    int wave = tid >> 6;
    if ((tid & 63) == 0) partw[wave] = make_float2(sc, su);
    __syncthreads();
    if (tid == 0) {
        float SC = partw[0].x + partw[1].x + partw[2].x + partw[3].x;
        float SU = partw[0].y + partw[1].y + partw[2].y + partw[3].y;
        const float invNT  = 1.0f / (float)(N_AGENTS * T_STEPS);
        const float invNT2 = 1.0f / (float)(N_AGENTS * T_STEPS * 2);
        out[0] = -SC * invNT + SU * invNT2;
    }
}

extern "C" void kernel_launch(void* const* d_in, const int* in_sizes, int n_in,
                              void* d_out, int out_size, void* d_ws, size_t ws_size,
                              hipStream_t stream) {
    const float* target_pos = (const float*)d_in[0];
    const float* logsigma   = (const float*)d_in[1];
    const float* x_inits    = (const float*)d_in[2];
    const float* W1         = (const float*)d_in[3];
    const float* b1         = (const float*)d_in[4];
    const float* W2         = (const float*)d_in[5];
    const float* b2         = (const float*)d_in[6];

    float*  pw   = (float*)d_ws;                          // 64 KB packed W1
    float2* sums = (float2*)((char*)d_ws + 64 * 1024);    // per-agent sums

    pack_kernel<<<HIDDEN, 32, 0, stream>>>(W1, pw);
    sim_kernel<<<N_AGENTS, 64, 0, stream>>>(target_pos, logsigma, x_inits,
                                            pw, b1, W2, b2, sums);
    reduce_kernel<<<1, 256, 0, stream>>>(sums, (float*)d_out);
}

// Round 20
// 651.617 us; speedup vs baseline: 3.3168x; 3.3168x over previous
//
#include <hip/hip_runtime.h>

#define T_STEPS 1000
#define DT 0.1f
#define HIDDEN 128
#define N_AGENTS 1024

typedef float v2f __attribute__((ext_vector_type(2)));

// tanh(x) = 1 - 2/(exp(2x)+1); exact at +/-inf, ~1e-7 rel error.
__device__ __forceinline__ float tanh_fast(float x) {
    float e = __expf(2.0f * x);
    return 1.0f - 2.0f * __builtin_amdgcn_rcpf(e + 1.0f);
}

// Opaque 8B load (R13-R18 proven residency mechanism).
__device__ __forceinline__ v2f opaque_load8(const float* p) {
    v2f v;
    asm volatile("global_load_dwordx2 %0, %1, off\n\ts_waitcnt vmcnt(0)"
                 : "=v"(v)
                 : "v"((unsigned long long)(uintptr_t)p)
                 : "memory");
    return v;
}

__device__ __forceinline__ float uniformf(float v) {
    return __builtin_bit_cast(float,
        __builtin_amdgcn_readfirstlane(__builtin_bit_cast(int, v)));
}

// 64-lane sum on the VALU pipe via DPP row ops (R11-R18 verified).
__device__ __forceinline__ float wave_sum_dpp(float x) {
    float t;
    #define DPPADD(ctrl, rmask)                                              \
        t = __builtin_bit_cast(float, __builtin_amdgcn_update_dpp(           \
                0, __builtin_bit_cast(int, x), ctrl, rmask, 0xf, false));    \
        x += t;
    DPPADD(0x111, 0xf)
    DPPADD(0x112, 0xf)
    DPPADD(0x114, 0xf)
    DPPADD(0x118, 0xf)
    DPPADD(0x142, 0xa)
    DPPADD(0x143, 0xc)
    #undef DPPADD
    return __builtin_bit_cast(float,
        __builtin_amdgcn_readlane(__builtin_bit_cast(int, x), 63));
}

// Pre-pack W1 into component-paired layout (R14-R18 verified).
__global__ void pack_kernel(const float* __restrict__ W1,
                            float* __restrict__ pw) {
    const int row = blockIdx.x;     // 128
    const int a   = threadIdx.x;    // 32
    const float* rp = W1 + row * 128;
    float* out = pw + row * 128;
    out[2*a]          = rp[3*a];
    out[2*a + 1]      = rp[3*a + 1];
    out[64 + 2*a]     = rp[3*a + 2];
    out[64 + 2*a + 1] = rp[96 + a];
}

// R18 two-wave role-asymmetric agent + K-OUTER BATCHED PUSHES.
// R18/R19 post-mortem: weights live in the AGPR half of the unified file;
// every use pays an accvgpr copy -> ~400 cyc/SIMD-step tax (the gap
// between modeled ~500 and measured 983). Fix: fetch each weight once per
// BATCH of states instead of once per state.
//  h=0 (consumer, ages 0..15): per step, consume slot (t&15) [zeroed after
//    consume], tail once, store state to a 4-entry reg buffer; push only
//    URGENT taps (k <= 2-(t&3)) in-step. Every 4 steps, a quarter-batch
//    pushes all LAZY taps k-outer (weight fetched once per tap, used for
//    up to 4 states).
//  h=1 (producer, ages 16..31): fully lazy. Twice per barrier window:
//    read 4 states from e4buf, k-outer push into a 20-slot ring
//    (idx = i+k, compile-time), ship 4 completed partials to part1,
//    rotate ring by 4.
// Sync: 2 barriers per 16-step superblock (same as R18); every part1/e4buf
// write-read pair is barrier-separated (ships s=16b+9..24 consumed >=1
// window later; e4buf slots disjoint between halves).
__global__ __launch_bounds__(128)
__attribute__((amdgpu_waves_per_eu(2, 2)))
void sim_kernel(const float* __restrict__ target_pos,
                const float* __restrict__ logsigma,
                const float* __restrict__ x_inits,
                const float* __restrict__ pw,
                const float* __restrict__ b1,
                const float* __restrict__ W2,
                const float* __restrict__ b2,
                float2* __restrict__ ws) {
    const int agent = blockIdx.x;
    const int tid  = threadIdx.x;   // 0..127
    const int h    = tid >> 6;      // 0 = consumer, 1 = producer
    const int lane = tid & 63;
    const int rowA = lane;
    const int rowB = lane + 64;

    __shared__ float2 part1[32][64];        // h=1 -> h=0 partial ring
    __shared__ float4 e4buf[16];            // state ring, 16-deep

    const float tx0 = uniformf(target_pos[0]), ty0 = uniformf(target_pos[1]);
    const float tx1 = uniformf(target_pos[2]), ty1 = uniformf(target_pos[3]);
    const float tx2 = uniformf(target_pos[4]), ty2 = uniformf(target_pos[5]);
    const float is0 = uniformf(1.0f / expf(logsigma[0]));
    const float is1 = uniformf(1.0f / expf(logsigma[1]));
    const float is2 = uniformf(1.0f / expf(logsigma[2]));

    // Paired weights for ages 16h..16h+15, rows A and B: 64 v2f pinned.
    v2f WxyA[16], WzcA[16], WxyB[16], WzcB[16];
    {
        const float* baseA = pw + rowA * 128;
        const float* baseB = pw + rowB * 128;
        #pragma unroll
        for (int i = 0; i < 16; ++i) {
            WxyA[i] = opaque_load8(baseA + 32 * h + 2 * i);
            WzcA[i] = opaque_load8(baseA + 64 + 32 * h + 2 * i);
            WxyB[i] = opaque_load8(baseB + 32 * h + 2 * i);
            WzcB[i] = opaque_load8(baseB + 64 + 32 * h + 2 * i);
        }
    }
    const float b1A = b1[rowA], b1B = b1[rowB];
    const float w20A = W2[rowA], w20B = W2[rowB];
    const float w21A = W2[HIDDEN + rowA], w21B = W2[HIDDEN + rowB];
    const float b2x = uniformf(b2[0]), b2y = uniformf(b2[1]);

    auto conc = [&](float px, float py) {
        float dx0 = px - tx0, dy0 = py - ty0;
        float dx1 = px - tx1, dy1 = py - ty1;
        float dx2 = px - tx2, dy2 = py - ty2;
        float cc  = is0 * __expf(-(dx0*dx0 + dy0*dy0) * is0);
        cc       += is1 * __expf(-(dx1*dx1 + dy1*dy1) * is1);
        cc       += is2 * __expf(-(dx2*dx2 + dy2*dy2) * is2);
        return cc;
    };

    float x  = uniformf(x_inits[3 * agent]);
    float y  = uniformf(x_inits[3 * agent + 1]);
    float th = uniformf(x_inits[3 * agent + 2]);
    float c  = conc(x, y);

    if (h == 0) {
        // ---------------- consumer wave ----------------
        v2f RA[16], RB[16];
        {   // seed slot s: sum_{k=s..15} W[k]·e(0)
            v2f exy0 = {x, y}, ezc0 = {th, c};
            v2f aA = {0.f,0.f}, aB = {0.f,0.f};
            #pragma unroll
            for (int k = 15; k >= 0; --k) {
                aA = WxyA[k]*exy0 + aA;  aA = WzcA[k]*ezc0 + aA;
                aB = WxyB[k]*exy0 + aB;  aB = WzcB[k]*ezc0 + aB;
                RA[k] = aA;  RB[k] = aB;
            }
            if (lane == 0) {
                float4 e0 = make_float4(x, y, th, c);
                #pragma unroll
                for (int m = 9; m < 16; ++m) e4buf[m] = e0;
                e4buf[0] = e0;
            }
        }
        __syncthreads();              // seed barrier (both waves)
        float2 pl = part1[0][lane];   // partial_1 for step 0
        v2f es_xy[4], es_zc[4];
        float S_c = 0.f, S_u = 0.f;

        auto h0_step = [&](int j, int s16) {
            float hA = fmaxf((RA[j].x + RA[j].y) + pl.x + b1A, 0.f);
            float hB = fmaxf((RB[j].x + RB[j].y) + pl.y + b1B, 0.f);
            RA[j] = (v2f){0.f, 0.f};   // recycle slot for step j+16
            RB[j] = (v2f){0.f, 0.f};
            float s0 = wave_sum_dpp(fmaf(w20A, hA, w20B * hB));
            float s1 = wave_sum_dpp(fmaf(w21A, hA, w21B * hB));
            float v  = tanh_fast(s0 + b2x);
            float wv = tanh_fast(s1 + b2y);
            S_u += v * v + wv * wv;
            float sn = __sinf(th), cs = __cosf(th);
            float dv = DT * v;
            x  = fmaf(dv, cs, x);
            y  = fmaf(dv, sn, y);
            th = fmaf(DT, wv, th);
            c  = conc(x, y);
            S_c += c;
            if (lane == 0) e4buf[(j + 1) & 15] = make_float4(x, y, th, c);
            v2f exy = {x, y}, ezc = {th, c};
            es_xy[j & 3] = exy;  es_zc[j & 3] = ezc;
            // urgent taps: k <= 2 - (j&3)
            #pragma unroll
            for (int k = 0; k < 3; ++k) {
                if (k <= 2 - (j & 3)) {
                    const int m = (j + 1 + k) & 15;
                    RA[m] = WxyA[k]*exy + RA[m];  RA[m] = WzcA[k]*ezc + RA[m];
                    RB[m] = WxyB[k]*exy + RB[m];  RB[m] = WzcB[k]*ezc + RB[m];
                }
            }
            pl = part1[(s16 + j + 1) & 31][lane];
        };
        auto h0_batch = [&](int q) {   // lazy taps of states e(.+4q+1..+4)
            #pragma unroll
            for (int kk = 0; kk < 16; ++kk) {
                #pragma unroll
                for (int i = 0; i < 4; ++i) {
                    if (kk >= 3 - i) {
                        const int m = (4*q + i + 1 + kk) & 15;
                        RA[m] = WxyA[kk]*es_xy[i] + RA[m];
                        RA[m] = WzcA[kk]*es_zc[i] + RA[m];
                        RB[m] = WxyB[kk]*es_xy[i] + RB[m];
                        RB[m] = WzcB[kk]*es_zc[i] + RB[m];
                    }
                }
            }
        };

        #pragma unroll 1
        for (int b = 0; b < 62; ++b) {
            const int s16 = (b & 1) << 4;
            __syncthreads();
            #pragma unroll
            for (int j = 0; j < 4; ++j) h0_step(j, s16);
            h0_batch(0);
            #pragma unroll
            for (int j = 4; j < 8; ++j) h0_step(j, s16);
            h0_batch(1);
            __syncthreads();
            #pragma unroll
            for (int j = 8; j < 12; ++j) h0_step(j, s16);
            h0_batch(2);
            #pragma unroll
            for (int j = 12; j < 16; ++j) h0_step(j, s16);
            h0_batch(3);
        }
        // remainder: steps 992..999 (b=62, s16=0)
        __syncthreads();
        #pragma unroll
        for (int j = 0; j < 4; ++j) h0_step(j, 0);
        h0_batch(0);
        #pragma unroll
        for (int j = 4; j < 8; ++j) h0_step(j, 0);

        if (lane == 0) ws[agent] = make_float2(S_c, S_u);
    } else {
        // ---------------- producer wave ----------------
        v2f PA[20], PB[20];
        {   // ring seed: PA[idx] = sum_{k=idx+1..15} W[k]·e(0), idx 0..14
            v2f exy0 = {x, y}, ezc0 = {th, c};
            #pragma unroll
            for (int i = 15; i < 20; ++i) { PA[i] = (v2f){0.f,0.f}; PB[i] = (v2f){0.f,0.f}; }
            v2f aA = {0.f,0.f}, aB = {0.f,0.f};
            #pragma unroll
            for (int k = 15; k >= 1; --k) {
                aA = WxyA[k]*exy0 + aA;  aA = WzcA[k]*ezc0 + aA;
                aB = WxyB[k]*exy0 + aB;  aB = WzcB[k]*ezc0 + aB;
                PA[k-1] = aA;  PB[k-1] = aB;
            }
            // part1 prefill s=0..8: full 16-tap sum
            v2f fA = WxyA[0]*exy0 + aA;  fA = WzcA[0]*ezc0 + fA;
            v2f fB = WxyB[0]*exy0 + aB;  fB = WzcB[0]*ezc0 + fB;
            float2 full = make_float2(fA.x + fA.y, fB.x + fB.y);
            #pragma unroll
            for (int s = 0; s <= 8; ++s) part1[s][lane] = full;
        }
        __syncthreads();              // seed barrier

        auto h1_batch = [&](int n, int b1w) {
            // read 4 states e(16b-7+4n .. +3 more): e4buf[(9+4n+i)&15]
            v2f pxy[4], pzc[4];
            #pragma unroll
            for (int i = 0; i < 4; ++i) {
                float4 e = e4buf[(9 + 4*n + i) & 15];
                pxy[i] = (v2f){e.x, e.y};
                pzc[i] = (v2f){e.z, e.w};
            }
            // k-outer push: each weight fetched once, used 4x
            #pragma unroll
            for (int kk = 0; kk < 16; ++kk) {
                #pragma unroll
                for (int i = 0; i < 4; ++i) {
                    const int idx = i + kk;
                    PA[idx] = WxyA[kk]*pxy[i] + PA[idx];
                    PA[idx] = WzcA[kk]*pzc[i] + PA[idx];
                    PB[idx] = WxyB[kk]*pxy[i] + PB[idx];
                    PB[idx] = WzcB[kk]*pzc[i] + PB[idx];
                }
            }
            // ship 4 completed partials: s = 16b + 9+4n + i
            #pragma unroll
            for (int i = 0; i < 4; ++i) {
                part1[(b1w * 16 + 9 + 4*n + i) & 31][lane] =
                    make_float2(PA[i].x + PA[i].y, PB[i].x + PB[i].y);
            }
            // rotate by 4
            #pragma unroll
            for (int i = 0; i < 16; ++i) { PA[i] = PA[i+4]; PB[i] = PB[i+4]; }
            #pragma unroll
            for (int i = 16; i < 20; ++i) { PA[i] = (v2f){0.f,0.f}; PB[i] = (v2f){0.f,0.f}; }
        };

        #pragma unroll 1
        for (int b = 0; b < 62; ++b) {
            const int b1w = b & 1;
            __syncthreads();
            h1_batch(0, b1w);
            h1_batch(1, b1w);
            __syncthreads();
            h1_batch(2, b1w);
            h1_batch(3, b1w);
        }
        __syncthreads();   // remainder barrier (match h0); nothing to ship
    }
}

__global__ void reduce_kernel(const float2* __restrict__ ws,
                              float* __restrict__ out) {
    const int tid = threadIdx.x;  // 256 threads
    float sc = 0.f, su = 0.f;
    for (int i = tid; i < N_AGENTS; i += 256) {
        float2 v = ws[i];
        sc += v.x;
        su += v.y;
    }
    #pragma unroll
    for (int off = 32; off > 0; off >>= 1) {
        sc += __shfl_xor(sc, off);
        su += __shfl_xor(su, off);
    }
    __shared__ float2 partw[4];
    int wave = tid >> 6;
    if ((tid & 63) == 0) partw[wave] = make_float2(sc, su);
    __syncthreads();
    if (tid == 0) {
        float SC = partw[0].x + partw[1].x + partw[2].x + partw[3].x;
        float SU = partw[0].y + partw[1].y + partw[2].y + partw[3].y;
        const float invNT  = 1.0f / (float)(N_AGENTS * T_STEPS);
        const float invNT2 = 1.0f / (float)(N_AGENTS * T_STEPS * 2);
        out[0] = -SC * invNT + SU * invNT2;
    }
}

extern "C" void kernel_launch(void* const* d_in, const int* in_sizes, int n_in,
                              void* d_out, int out_size, void* d_ws, size_t ws_size,
                              hipStream_t stream) {
    const float* target_pos = (const float*)d_in[0];
    const float* logsigma   = (const float*)d_in[1];
    const float* x_inits    = (const float*)d_in[2];
    const float* W1         = (const float*)d_in[3];
    const float* b1         = (const float*)d_in[4];
    const float* W2         = (const float*)d_in[5];
    const float* b2         = (const float*)d_in[6];

    float*  pw   = (float*)d_ws;                          // 64 KB packed W1
    float2* sums = (float2*)((char*)d_ws + 64 * 1024);    // per-agent sums

    pack_kernel<<<HIDDEN, 32, 0, stream>>>(W1, pw);
    sim_kernel<<<N_AGENTS, 128, 0, stream>>>(target_pos, logsigma, x_inits,
                                             pw, b1, W2, b2, sums);
    reduce_kernel<<<1, 256, 0, stream>>>(sums, (float*)d_out);
}